// Round 6
// baseline (105.365 us; speedup 1.0000x reference)
//
#include <hip/hip_runtime.h>
#include <math.h>

#define NTOT 6148
#define NB 64
#define DM 512
#define SCALE_F 0.17677669529663687f

typedef __attribute__((ext_vector_type(8))) short bf16x8;
typedef __attribute__((ext_vector_type(4))) short bf16x4;
typedef __attribute__((ext_vector_type(4))) float f32x4;

__device__ __forceinline__ short f2bf(float f) {
  union { float f; unsigned u; } v; v.f = f;
  unsigned r = (v.u + 0x7fffu + ((v.u >> 16) & 1u)) >> 16;
  return (short)r;
}
__device__ __forceinline__ float bf2f(short s) {
  union { unsigned u; float f; } v;
  v.u = ((unsigned)(unsigned short)s) << 16;
  return v.f;
}

__device__ __forceinline__ void gl_lds16(const short* g, void* l) {
  auto gp = (const __attribute__((address_space(1))) unsigned*)(unsigned long long)(g);
  auto lp = (__attribute__((address_space(3))) unsigned*)(unsigned long long)(uintptr_t)l;
  __builtin_amdgcn_global_load_lds(gp, lp, 16, 0, 0);
}

// ---------------- starts from batch array ----------------
__global__ __launch_bounds__(256) void k_starts(const int* __restrict__ batch,
                                                int* __restrict__ starts) {
  int i = blockIdx.x * 256 + threadIdx.x;
  if (i >= NTOT) return;
  int b = batch[i];
  if (i == 0) starts[b] = 0;
  else if (batch[i - 1] != b) starts[b] = i;
  if (i == NTOT - 1) starts[NB] = NTOT;
}

// ---------------- f32 -> bf16 conversion (x + 4 weight matrices) ----------------
__global__ __launch_bounds__(256) void k_cvt(const float* __restrict__ x,
                                             const float* __restrict__ wq,
                                             const float* __restrict__ wk,
                                             const float* __restrict__ wv,
                                             const float* __restrict__ wp,
                                             short* __restrict__ xb,
                                             short* __restrict__ wqb,
                                             short* __restrict__ wkb,
                                             short* __restrict__ wvb,
                                             short* __restrict__ wpb) {
  const int bid = blockIdx.x;
  const float* s; short* d; long off;
  if (bid < 1537) {  // 1537*2048 == NTOT*512 exactly
    s = x; d = xb;
    off = ((long)bid * 256 + threadIdx.x) * 8;
  } else {
    int wi = (bid - 1537) >> 7;  // 128 blocks per 512x512 matrix
    s = (wi == 0) ? wq : (wi == 1) ? wk : (wi == 2) ? wv : wp;
    d = (wi == 0) ? wqb : (wi == 1) ? wkb : (wi == 2) ? wvb : wpb;
    off = ((long)((bid - 1537) & 127) * 256 + threadIdx.x) * 8;
  }
  float4 v0 = *(const float4*)(s + off);
  float4 v1 = *(const float4*)(s + off + 4);
  bf16x8 o;
  o[0] = f2bf(v0.x); o[1] = f2bf(v0.y); o[2] = f2bf(v0.z); o[3] = f2bf(v0.w);
  o[4] = f2bf(v1.x); o[5] = f2bf(v1.y); o[6] = f2bf(v1.z); o[7] = f2bf(v1.w);
  *(bf16x8*)(d + off) = o;
}

// ---------------- bf16 MFMA GEMM: C = A[M][512](bf16) @ W[N][512](bf16)^T + bias ----
// 128x128 tile, BK=32, 4 waves (2x2 of 64x64). BF16OUT selects output dtype.
template <bool BF16OUT>
__global__ __launch_bounds__(256) void k_gemm_mfma(
    const short* __restrict__ Abf,
    const short* __restrict__ W0, const short* __restrict__ W1, const short* __restrict__ W2,
    const float* __restrict__ b0, const float* __restrict__ b1, const float* __restrict__ b2,
    const float* __restrict__ resid, void* __restrict__ Cv, int ldc, int M) {
  __shared__ __align__(16) short As[128][32];
  __shared__ __align__(16) short Bs[128][32];
  const int tid = threadIdx.x;
  const int w = tid >> 6, l = tid & 63;
  const int m0 = blockIdx.x * 128;
  const int n0 = blockIdx.y * 128;
  const int sel = n0 >> 9;
  const short* Wt = (sel == 0) ? W0 : (sel == 1) ? W1 : W2;
  const float* bt = (sel == 0) ? b0 : (sel == 1) ? b1 : b2;
  const int nl0 = n0 & 511;
  const int wr = w >> 1, wc = w & 1;
  const int lr = l >> 2;        // row within 16-row group (64B rows)
  const int lc = (l & 3) * 8;   // short offset of this lane's 16B chunk

  f32x4 acc[4][4];
#pragma unroll
  for (int m = 0; m < 4; m++)
#pragma unroll
    for (int n = 0; n < 4; n++) acc[m][n] = (f32x4){0.f, 0.f, 0.f, 0.f};

  for (int k0 = 0; k0 < 512; k0 += 32) {
    {
      const int r0 = w * 32 + lr, r1 = r0 + 16;
      gl_lds16(Abf + (long)min(m0 + r0, M - 1) * 512 + k0 + lc, &As[w * 32][0]);
      gl_lds16(Abf + (long)min(m0 + r1, M - 1) * 512 + k0 + lc, &As[w * 32 + 16][0]);
      gl_lds16(Wt + (long)(nl0 + r0) * 512 + k0 + lc, &Bs[w * 32][0]);
      gl_lds16(Wt + (long)(nl0 + r1) * 512 + k0 + lc, &Bs[w * 32 + 16][0]);
    }
    __syncthreads();
    const int fr = l & 15, fs = (l >> 4) * 8;
    bf16x8 af[4], bfr[4];
#pragma unroll
    for (int m = 0; m < 4; m++) af[m] = *(const bf16x8*)&As[wr * 64 + m * 16 + fr][fs];
#pragma unroll
    for (int n = 0; n < 4; n++) bfr[n] = *(const bf16x8*)&Bs[wc * 64 + n * 16 + fr][fs];
#pragma unroll
    for (int m = 0; m < 4; m++)
#pragma unroll
      for (int n = 0; n < 4; n++)
        acc[m][n] = __builtin_amdgcn_mfma_f32_16x16x32_bf16(af[m], bfr[n], acc[m][n], 0, 0, 0);
    __syncthreads();
  }

  // epilogue: C/D layout col=lane&15, row=(lane>>4)*4+j
  const int er = (l >> 4) * 4, ec = l & 15;
#pragma unroll
  for (int n = 0; n < 4; n++) {
    const int col = n0 + wc * 64 + n * 16 + ec;
    const float bv = bt[col & 511];
#pragma unroll
    for (int m = 0; m < 4; m++) {
      const int rowb = m0 + wr * 64 + m * 16 + er;
#pragma unroll
      for (int j = 0; j < 4; j++) {
        const int row = rowb + j;
        if (row < M) {
          float v = acc[m][n][j] + bv;
          if (resid) v += resid[(long)row * 512 + col];
          if (BF16OUT) ((short*)Cv)[(long)row * ldc + col] = f2bf(v);
          else ((float*)Cv)[(long)row * ldc + col] = v;
        }
      }
    }
  }
}

// ---------------- MFMA attention: one block per (h, b), 4 waves x 32 q-rows ----
// Bias is staged coalesced into each wave's P strip (bf16), read as fragments,
// then overwritten by P (per-wave in-order LDS makes the WAR safe).
__global__ __launch_bounds__(256) void k_attn(const short* __restrict__ QKVbf,
                                              const float* __restrict__ bias,
                                              const int* __restrict__ starts,
                                              short* __restrict__ Obf) {
  __shared__ __align__(16) short Qb[128][40];   // +8 pad: 20-dword rows spread banks
  __shared__ __align__(16) short Kb[128][40];
  __shared__ __align__(16) short Vtb[32][136];  // V transposed (rows = d)
  __shared__ __align__(16) short Ps[128][136];  // bias strip, then P (per-wave 32 rows)
  const int h = blockIdx.x, b = blockIdx.y;
  const int s0 = starts[b], cnt = starts[b + 1] - s0;
  const int tid = threadIdx.x;
  // ---- stage Q, K, V^T (bf16 in, zero-pad rows >= cnt) ----
  {
    const int r0 = tid >> 2;          // 0..63
    const int c = (tid & 3) * 8;      // 0,8,16,24 shorts
    const bf16x8 zz = {0, 0, 0, 0, 0, 0, 0, 0};
#pragma unroll
    for (int rr = r0; rr < 128; rr += 64) {
      const bool valid = rr < cnt;
      const short* rowp = QKVbf + (long)(s0 + (valid ? rr : 0)) * 1536 + h * 32 + c;
      bf16x8 qv = valid ? *(const bf16x8*)rowp : zz;
      bf16x8 kv = valid ? *(const bf16x8*)(rowp + 512) : zz;
      bf16x8 vv = valid ? *(const bf16x8*)(rowp + 1024) : zz;
      *(bf16x8*)&Qb[rr][c] = qv;
      *(bf16x8*)&Kb[rr][c] = kv;
#pragma unroll
      for (int i = 0; i < 8; i++) Vtb[c + i][rr] = vv[i];
    }
  }
  const int l = tid & 63, w = tid >> 6;
  const int wq0 = w * 32;
  const bool active = wq0 < cnt;
  const float* bbase = bias + ((long)(b * 16 + h) << 14);
  // ---- stage this wave's 32x128 bias panel -> bf16 into its own P strip ----
  if (active) {
    const int rcol = (l & 31) * 4;   // float4 column
    const int rhalf = l >> 5;        // two rows per iteration
#pragma unroll
    for (int t = 0; t < 16; t++) {
      const int r = t * 2 + rhalf;   // local row 0..31
      const float4 bv4 = *(const float4*)(bbase + (long)(wq0 + r) * 128 + rcol);
      bf16x4 o;
      o[0] = f2bf(bv4.x); o[1] = f2bf(bv4.y); o[2] = f2bf(bv4.z); o[3] = f2bf(bv4.w);
      *(bf16x4*)&Ps[wq0 + r][rcol] = o;
    }
  }
  __syncthreads();
  if (!active) return;               // no barriers after this point
  const int lg = l >> 4, lk = l & 15, fs = lg * 8;

  // ---- S = Q K^T (16 MFMA) ----
  f32x4 S[2][8];
  bf16x8 aq[2];
#pragma unroll
  for (int m = 0; m < 2; m++) aq[m] = *(const bf16x8*)&Qb[wq0 + m * 16 + lk][fs];
#pragma unroll
  for (int n = 0; n < 8; n++) {
    const bf16x8 bk8 = *(const bf16x8*)&Kb[n * 16 + lk][fs];
#pragma unroll
    for (int m = 0; m < 2; m++)
      S[m][n] = __builtin_amdgcn_mfma_f32_16x16x32_bf16(aq[m], bk8,
                                                        (f32x4){0.f, 0.f, 0.f, 0.f}, 0, 0, 0);
  }

  // ---- bias(LDS) + scale + mask + softmax; unnormalized P -> LDS bf16 ----
  float invs[2][4];
#pragma unroll
  for (int m = 0; m < 2; m++) {
    const int qb0 = wq0 + m * 16 + lg * 4;
#pragma unroll
    for (int n = 0; n < 8; n++) {
      const int k = n * 16 + lk;
      const bool kok = k < cnt;
#pragma unroll
      for (int j = 0; j < 4; j++) {
        const float sv = S[m][n][j] * SCALE_F + bf2f(Ps[qb0 + j][n * 16 + lk]);
        S[m][n][j] = kok ? sv : -1e30f;
      }
    }
#pragma unroll
    for (int j = 0; j < 4; j++) {
      float mx = S[m][0][j];
#pragma unroll
      for (int n = 1; n < 8; n++) mx = fmaxf(mx, S[m][n][j]);
      mx = fmaxf(mx, __shfl_xor(mx, 1));
      mx = fmaxf(mx, __shfl_xor(mx, 2));
      mx = fmaxf(mx, __shfl_xor(mx, 4));
      mx = fmaxf(mx, __shfl_xor(mx, 8));
      float sum = 0.f;
#pragma unroll
      for (int n = 0; n < 8; n++) {
        const float p = __expf(S[m][n][j] - mx);
        S[m][n][j] = p;
        sum += p;
      }
      sum += __shfl_xor(sum, 1);
      sum += __shfl_xor(sum, 2);
      sum += __shfl_xor(sum, 4);
      sum += __shfl_xor(sum, 8);
      invs[m][j] = 1.f / sum;
      const int qloc = qb0 + j;
#pragma unroll
      for (int n = 0; n < 8; n++) Ps[qloc][n * 16 + lk] = f2bf(S[m][n][j]);
    }
  }

  // ---- O = P V (16 MFMA), same-wave LDS RAW ----
  f32x4 O[2][2];
#pragma unroll
  for (int m = 0; m < 2; m++)
#pragma unroll
    for (int dt = 0; dt < 2; dt++) O[m][dt] = (f32x4){0.f, 0.f, 0.f, 0.f};
#pragma unroll
  for (int kc = 0; kc < 4; kc++) {
    bf16x8 pa[2], vb[2];
#pragma unroll
    for (int m = 0; m < 2; m++) pa[m] = *(const bf16x8*)&Ps[wq0 + m * 16 + lk][kc * 32 + fs];
#pragma unroll
    for (int dt = 0; dt < 2; dt++) vb[dt] = *(const bf16x8*)&Vtb[dt * 16 + lk][kc * 32 + fs];
#pragma unroll
    for (int m = 0; m < 2; m++)
#pragma unroll
      for (int dt = 0; dt < 2; dt++)
        O[m][dt] = __builtin_amdgcn_mfma_f32_16x16x32_bf16(pa[m], vb[dt], O[m][dt], 0, 0, 0);
  }
  // ---- store O (bf16), fold in 1/sum ----
#pragma unroll
  for (int m = 0; m < 2; m++) {
    const int qb0 = wq0 + m * 16 + lg * 4;
#pragma unroll
    for (int j = 0; j < 4; j++) {
      if (qb0 + j < cnt) {
        short* orow = Obf + (long)(s0 + qb0 + j) * 512 + h * 32;
#pragma unroll
        for (int dt = 0; dt < 2; dt++)
          orow[dt * 16 + lk] = f2bf(O[m][dt][j] * invs[m][j]);
      }
    }
  }
}

// ---------------- LayerNorm (residual pre-added), one wave per row ----------------
__global__ __launch_bounds__(256) void k_lnp(const float* __restrict__ pre,
                                             const float* __restrict__ lw,
                                             const float* __restrict__ lb,
                                             float* __restrict__ out) {
  const int row = blockIdx.x * 4 + (threadIdx.x >> 6);
  if (row >= NTOT) return;
  const int lane = threadIdx.x & 63;
  const float* pr = pre + (long)row * 512 + lane * 8;
  float4 p0 = *(const float4*)pr;
  float4 p1 = *(const float4*)(pr + 4);
  float v[8] = {p0.x, p0.y, p0.z, p0.w, p1.x, p1.y, p1.z, p1.w};
  float s = 0.f, s2 = 0.f;
#pragma unroll
  for (int j = 0; j < 8; j++) { s += v[j]; s2 += v[j] * v[j]; }
#pragma unroll
  for (int off = 32; off > 0; off >>= 1) {
    s += __shfl_xor(s, off);
    s2 += __shfl_xor(s2, off);
  }
  const float mu = s * (1.f / 512.f);
  const float var = s2 * (1.f / 512.f) - mu * mu;
  const float inv = rsqrtf(var + 1e-5f);
  float4 w0 = *(const float4*)&lw[lane * 8];
  float4 w1 = *(const float4*)&lw[lane * 8 + 4];
  float4 b0 = *(const float4*)&lb[lane * 8];
  float4 b1 = *(const float4*)&lb[lane * 8 + 4];
  float4 o0 = make_float4((v[0] - mu) * inv * w0.x + b0.x, (v[1] - mu) * inv * w0.y + b0.y,
                          (v[2] - mu) * inv * w0.z + b0.z, (v[3] - mu) * inv * w0.w + b0.w);
  float4 o1 = make_float4((v[4] - mu) * inv * w1.x + b1.x, (v[5] - mu) * inv * w1.y + b1.y,
                          (v[6] - mu) * inv * w1.z + b1.z, (v[7] - mu) * inv * w1.w + b1.w);
  float* dst = out + (long)row * 512 + lane * 8;
  *(float4*)dst = o0;
  *(float4*)(dst + 4) = o1;
}

extern "C" void kernel_launch(void* const* d_in, const int* in_sizes, int n_in,
                              void* d_out, int out_size, void* d_ws, size_t ws_size,
                              hipStream_t stream) {
  const float* x = (const float*)d_in[0];
  const float* attn_bias = (const float*)d_in[1];
  const float* Wq = (const float*)d_in[2];
  const float* bq = (const float*)d_in[3];
  const float* Wk = (const float*)d_in[4];
  const float* bk = (const float*)d_in[5];
  const float* Wv = (const float*)d_in[6];
  const float* bv = (const float*)d_in[7];
  const float* Wp = (const float*)d_in[8];
  const float* bp = (const float*)d_in[9];
  const float* ln_w = (const float*)d_in[10];
  const float* ln_b = (const float*)d_in[11];
  const int* batch = (const int*)d_in[12];
  float* out = (float*)d_out;

  char* ws = (char*)d_ws;
  int* starts = (int*)ws;                        // 65 ints (512B reserved)
  short* Xbf = (short*)(ws + 512);               // NTOT x 512 bf16
  short* Wqb = Xbf + (long)NTOT * 512;
  short* Wkb = Wqb + 512 * 512;
  short* Wvb = Wkb + 512 * 512;
  short* Wpb = Wvb + 512 * 512;
  short* QKVbf = Wpb + 512 * 512;                // NTOT x 1536 bf16
  short* Obf = Xbf;                              // reuse: Xbf dead after QKV GEMM
  float* proj = (float*)QKVbf;                   // reuse: QKVbf dead after attention

  k_starts<<<(NTOT + 255) / 256, 256, 0, stream>>>(batch, starts);
  k_cvt<<<1537 + 4 * 128, 256, 0, stream>>>(x, Wq, Wk, Wv, Wp, Xbf, Wqb, Wkb, Wvb, Wpb);

  dim3 gq((NTOT + 127) / 128, 12);  // fused QKV: N = 1536, bf16 out
  k_gemm_mfma<true><<<gq, 256, 0, stream>>>(Xbf, Wqb, Wkb, Wvb, bq, bk, bv,
                                            nullptr, QKVbf, 1536, NTOT);

  dim3 ga(16, NB);  // (h, b)
  k_attn<<<ga, 256, 0, stream>>>(QKVbf, attn_bias, starts, Obf);

  dim3 gp((NTOT + 127) / 128, 4);  // proj: N = 512, residual fused, f32 out
  k_gemm_mfma<false><<<gp, 256, 0, stream>>>(Obf, Wpb, Wpb, Wpb, bp, bp, bp,
                                             x, proj, 512, NTOT);

  k_lnp<<<(NTOT + 3) / 4, 256, 0, stream>>>(proj, ln_w, ln_b, out);
}

// Round 7
// 101.793 us; speedup vs baseline: 1.0351x; 1.0351x over previous
//
#include <hip/hip_runtime.h>
#include <math.h>

#define NTOT 6148
#define NB 64
#define DM 512
#define SCALE_F 0.17677669529663687f

typedef __attribute__((ext_vector_type(8))) short bf16x8;
typedef __attribute__((ext_vector_type(4))) short bf16x4;
typedef __attribute__((ext_vector_type(4))) float f32x4;

__device__ __forceinline__ short f2bf(float f) {
  union { float f; unsigned u; } v; v.f = f;
  unsigned r = (v.u + 0x7fffu + ((v.u >> 16) & 1u)) >> 16;
  return (short)r;
}
__device__ __forceinline__ float bf2f(short s) {
  union { unsigned u; float f; } v;
  v.u = ((unsigned)(unsigned short)s) << 16;
  return v.f;
}

__device__ __forceinline__ void gl_lds16(const short* g, void* l) {
  auto gp = (const __attribute__((address_space(1))) unsigned*)(unsigned long long)(g);
  auto lp = (__attribute__((address_space(3))) unsigned*)(unsigned long long)(uintptr_t)l;
  __builtin_amdgcn_global_load_lds(gp, lp, 16, 0, 0);
}

// ---------------- starts from batch array ----------------
__global__ __launch_bounds__(256) void k_starts(const int* __restrict__ batch,
                                                int* __restrict__ starts) {
  int i = blockIdx.x * 256 + threadIdx.x;
  if (i >= NTOT) return;
  int b = batch[i];
  if (i == 0) starts[b] = 0;
  else if (batch[i - 1] != b) starts[b] = i;
  if (i == NTOT - 1) starts[NB] = NTOT;
}

// ---------------- f32 -> bf16 conversion (x + 4 weight matrices) ----------------
__global__ __launch_bounds__(256) void k_cvt(const float* __restrict__ x,
                                             const float* __restrict__ wq,
                                             const float* __restrict__ wk,
                                             const float* __restrict__ wv,
                                             const float* __restrict__ wp,
                                             short* __restrict__ xb,
                                             short* __restrict__ wqb,
                                             short* __restrict__ wkb,
                                             short* __restrict__ wvb,
                                             short* __restrict__ wpb) {
  const int bid = blockIdx.x;
  const float* s; short* d; long off;
  if (bid < 1537) {  // 1537*2048 == NTOT*512 exactly
    s = x; d = xb;
    off = ((long)bid * 256 + threadIdx.x) * 8;
  } else {
    int wi = (bid - 1537) >> 7;  // 128 blocks per 512x512 matrix
    s = (wi == 0) ? wq : (wi == 1) ? wk : (wi == 2) ? wv : wp;
    d = (wi == 0) ? wqb : (wi == 1) ? wkb : (wi == 2) ? wvb : wpb;
    off = ((long)((bid - 1537) & 127) * 256 + threadIdx.x) * 8;
  }
  float4 v0 = *(const float4*)(s + off);
  float4 v1 = *(const float4*)(s + off + 4);
  bf16x8 o;
  o[0] = f2bf(v0.x); o[1] = f2bf(v0.y); o[2] = f2bf(v0.z); o[3] = f2bf(v0.w);
  o[4] = f2bf(v1.x); o[5] = f2bf(v1.y); o[6] = f2bf(v1.z); o[7] = f2bf(v1.w);
  *(bf16x8*)(d + off) = o;
}

// ---------------- bf16 MFMA GEMM: C = A[M][512](bf16) @ W[N][512](bf16)^T + bias ----
// 128x128 tile, BK=32, 4 waves (2x2 of 64x64). BF16OUT selects output dtype.
template <bool BF16OUT>
__global__ __launch_bounds__(256) void k_gemm_mfma(
    const short* __restrict__ Abf,
    const short* __restrict__ W0, const short* __restrict__ W1, const short* __restrict__ W2,
    const float* __restrict__ b0, const float* __restrict__ b1, const float* __restrict__ b2,
    const float* __restrict__ resid, void* __restrict__ Cv, int ldc, int M) {
  __shared__ __align__(16) short As[128][32];
  __shared__ __align__(16) short Bs[128][32];
  const int tid = threadIdx.x;
  const int w = tid >> 6, l = tid & 63;
  const int m0 = blockIdx.x * 128;
  const int n0 = blockIdx.y * 128;
  const int sel = n0 >> 9;
  const short* Wt = (sel == 0) ? W0 : (sel == 1) ? W1 : W2;
  const float* bt = (sel == 0) ? b0 : (sel == 1) ? b1 : b2;
  const int nl0 = n0 & 511;
  const int wr = w >> 1, wc = w & 1;
  const int lr = l >> 2;        // row within 16-row group (64B rows)
  const int lc = (l & 3) * 8;   // short offset of this lane's 16B chunk

  f32x4 acc[4][4];
#pragma unroll
  for (int m = 0; m < 4; m++)
#pragma unroll
    for (int n = 0; n < 4; n++) acc[m][n] = (f32x4){0.f, 0.f, 0.f, 0.f};

  for (int k0 = 0; k0 < 512; k0 += 32) {
    {
      const int r0 = w * 32 + lr, r1 = r0 + 16;
      gl_lds16(Abf + (long)min(m0 + r0, M - 1) * 512 + k0 + lc, &As[w * 32][0]);
      gl_lds16(Abf + (long)min(m0 + r1, M - 1) * 512 + k0 + lc, &As[w * 32 + 16][0]);
      gl_lds16(Wt + (long)(nl0 + r0) * 512 + k0 + lc, &Bs[w * 32][0]);
      gl_lds16(Wt + (long)(nl0 + r1) * 512 + k0 + lc, &Bs[w * 32 + 16][0]);
    }
    __syncthreads();
    const int fr = l & 15, fs = (l >> 4) * 8;
    bf16x8 af[4], bfr[4];
#pragma unroll
    for (int m = 0; m < 4; m++) af[m] = *(const bf16x8*)&As[wr * 64 + m * 16 + fr][fs];
#pragma unroll
    for (int n = 0; n < 4; n++) bfr[n] = *(const bf16x8*)&Bs[wc * 64 + n * 16 + fr][fs];
#pragma unroll
    for (int m = 0; m < 4; m++)
#pragma unroll
      for (int n = 0; n < 4; n++)
        acc[m][n] = __builtin_amdgcn_mfma_f32_16x16x32_bf16(af[m], bfr[n], acc[m][n], 0, 0, 0);
    __syncthreads();
  }

  // epilogue: C/D layout col=lane&15, row=(lane>>4)*4+j
  const int er = (l >> 4) * 4, ec = l & 15;
#pragma unroll
  for (int n = 0; n < 4; n++) {
    const int col = n0 + wc * 64 + n * 16 + ec;
    const float bv = bt[col & 511];
#pragma unroll
    for (int m = 0; m < 4; m++) {
      const int rowb = m0 + wr * 64 + m * 16 + er;
#pragma unroll
      for (int j = 0; j < 4; j++) {
        const int row = rowb + j;
        if (row < M) {
          float v = acc[m][n][j] + bv;
          if (resid) v += resid[(long)row * 512 + col];
          if (BF16OUT) ((short*)Cv)[(long)row * ldc + col] = f2bf(v);
          else ((float*)Cv)[(long)row * ldc + col] = v;
        }
      }
    }
  }
}

// ---------------- MFMA attention: one block per (h, b), 4 waves x 32 q-rows ----
// Q/K fragments loaded directly from global (L2-hot). V staged wave-locally to
// LDS transposed; bias staged coalesced into each wave's own P strip (bf16).
// Single barrier (V visibility); all P traffic is wave-local in-order LDS.
__global__ __launch_bounds__(256, 3) void k_attn(const short* __restrict__ QKVbf,
                                                 const float* __restrict__ bias,
                                                 const int* __restrict__ starts,
                                                 short* __restrict__ Obf) {
  __shared__ __align__(16) short Vtb[32][136];  // V transposed (rows = d)
  __shared__ __align__(16) short Ps[128][136];  // bias strip, then P (per-wave 32 rows)
  const int h = blockIdx.x, b = blockIdx.y;
  const int s0 = starts[b], cnt = starts[b + 1] - s0;
  const int tid = threadIdx.x, l = tid & 63, w = tid >> 6;
  const int wq0 = w * 32;
  const int lg = l >> 4, lk = l & 15, fs = lg * 8;
  const bool active = wq0 < cnt;

  // ---- issue V loads (own 32 k-rows, clamped => finite data) ----
  const int u = l >> 2, c = (l & 3) * 8;
  const short* vbase = QKVbf + 1024 + h * 32 + c;
  const bf16x8 v0 = *(const bf16x8*)(vbase + (long)(s0 + min(wq0 + u, cnt - 1)) * 1536);
  const bf16x8 v1 = *(const bf16x8*)(vbase + (long)(s0 + min(wq0 + u + 16, cnt - 1)) * 1536);

  // ---- issue Q/K fragment loads + bias loads (bulk, all in flight) ----
  bf16x8 aq[2], bk[8];
  float4 bv[16];
  const int rcol = (l & 31) * 4, rhalf = l >> 5;
  if (active) {
    const short* qbase = QKVbf + h * 32 + fs;
#pragma unroll
    for (int m = 0; m < 2; m++)
      aq[m] = *(const bf16x8*)(qbase + (long)(s0 + min(wq0 + m * 16 + lk, cnt - 1)) * 1536);
#pragma unroll
    for (int n = 0; n < 8; n++)
      bk[n] = *(const bf16x8*)(qbase + 512 + (long)(s0 + min(n * 16 + lk, cnt - 1)) * 1536);
    const float* bbase = bias + ((long)(b * 16 + h) << 14) + (long)wq0 * 128;
#pragma unroll
    for (int t = 0; t < 16; t++)
      bv[t] = *(const float4*)(bbase + (long)(t * 2 + rhalf) * 128 + rcol);
  }

  // ---- V scatter-transpose into LDS (all waves; rows >= cnt hold finite data,
  //      they are multiplied by P==0) ----
#pragma unroll
  for (int i = 0; i < 8; i++) Vtb[c + i][wq0 + u] = v0[i];
#pragma unroll
  for (int i = 0; i < 8; i++) Vtb[c + i][wq0 + u + 16] = v1[i];

  f32x4 S[2][8];
  float invs[2][4];
  if (active) {
    // ---- bias -> own Ps strip (bf16) ----
#pragma unroll
    for (int t = 0; t < 16; t++) {
      bf16x4 o;
      o[0] = f2bf(bv[t].x); o[1] = f2bf(bv[t].y); o[2] = f2bf(bv[t].z); o[3] = f2bf(bv[t].w);
      *(bf16x4*)&Ps[wq0 + t * 2 + rhalf][rcol] = o;
    }
    // ---- S = Q K^T (16 MFMA) ----
#pragma unroll
    for (int n = 0; n < 8; n++)
#pragma unroll
      for (int m = 0; m < 2; m++)
        S[m][n] = __builtin_amdgcn_mfma_f32_16x16x32_bf16(aq[m], bk[n],
                                                          (f32x4){0.f, 0.f, 0.f, 0.f}, 0, 0, 0);
    // ---- bias(LDS) + scale + mask + softmax; unnormalized P -> own strip ----
#pragma unroll
    for (int m = 0; m < 2; m++) {
      const int qb0 = wq0 + m * 16 + lg * 4;
#pragma unroll
      for (int n = 0; n < 8; n++) {
        const int k = n * 16 + lk;
        const bool kok = k < cnt;
#pragma unroll
        for (int j = 0; j < 4; j++) {
          const float sv = S[m][n][j] * SCALE_F + bf2f(Ps[qb0 + j][n * 16 + lk]);
          S[m][n][j] = kok ? sv : -1e30f;
        }
      }
#pragma unroll
      for (int j = 0; j < 4; j++) {
        float mx = S[m][0][j];
#pragma unroll
        for (int n = 1; n < 8; n++) mx = fmaxf(mx, S[m][n][j]);
        mx = fmaxf(mx, __shfl_xor(mx, 1));
        mx = fmaxf(mx, __shfl_xor(mx, 2));
        mx = fmaxf(mx, __shfl_xor(mx, 4));
        mx = fmaxf(mx, __shfl_xor(mx, 8));
        float sum = 0.f;
#pragma unroll
        for (int n = 0; n < 8; n++) {
          const float p = __expf(S[m][n][j] - mx);
          S[m][n][j] = p;
          sum += p;
        }
        sum += __shfl_xor(sum, 1);
        sum += __shfl_xor(sum, 2);
        sum += __shfl_xor(sum, 4);
        sum += __shfl_xor(sum, 8);
        invs[m][j] = 1.f / sum;
        const int qloc = qb0 + j;
#pragma unroll
        for (int n = 0; n < 8; n++) Ps[qloc][n * 16 + lk] = f2bf(S[m][n][j]);
      }
    }
  }

  __syncthreads();  // V (cross-wave) visibility; P/bias are wave-local
  if (!active) return;

  // ---- O = P V (16 MFMA) ----
  f32x4 O[2][2];
#pragma unroll
  for (int m = 0; m < 2; m++)
#pragma unroll
    for (int dt = 0; dt < 2; dt++) O[m][dt] = (f32x4){0.f, 0.f, 0.f, 0.f};
#pragma unroll
  for (int kc = 0; kc < 4; kc++) {
    bf16x8 pa[2], vb[2];
#pragma unroll
    for (int m = 0; m < 2; m++) pa[m] = *(const bf16x8*)&Ps[wq0 + m * 16 + lk][kc * 32 + fs];
#pragma unroll
    for (int dt = 0; dt < 2; dt++) vb[dt] = *(const bf16x8*)&Vtb[dt * 16 + lk][kc * 32 + fs];
#pragma unroll
    for (int m = 0; m < 2; m++)
#pragma unroll
      for (int dt = 0; dt < 2; dt++)
        O[m][dt] = __builtin_amdgcn_mfma_f32_16x16x32_bf16(pa[m], vb[dt], O[m][dt], 0, 0, 0);
  }
  // ---- store O (bf16), fold in 1/sum ----
#pragma unroll
  for (int m = 0; m < 2; m++) {
    const int qb0 = wq0 + m * 16 + lg * 4;
#pragma unroll
    for (int j = 0; j < 4; j++) {
      if (qb0 + j < cnt) {
        short* orow = Obf + (long)(s0 + qb0 + j) * 512 + h * 32;
#pragma unroll
        for (int dt = 0; dt < 2; dt++)
          orow[dt * 16 + lk] = f2bf(O[m][dt][j] * invs[m][j]);
      }
    }
  }
}

// ---------------- LayerNorm (residual pre-added), one wave per row ----------------
__global__ __launch_bounds__(256) void k_lnp(const float* __restrict__ pre,
                                             const float* __restrict__ lw,
                                             const float* __restrict__ lb,
                                             float* __restrict__ out) {
  const int row = blockIdx.x * 4 + (threadIdx.x >> 6);
  if (row >= NTOT) return;
  const int lane = threadIdx.x & 63;
  const float* pr = pre + (long)row * 512 + lane * 8;
  float4 p0 = *(const float4*)pr;
  float4 p1 = *(const float4*)(pr + 4);
  float v[8] = {p0.x, p0.y, p0.z, p0.w, p1.x, p1.y, p1.z, p1.w};
  float s = 0.f, s2 = 0.f;
#pragma unroll
  for (int j = 0; j < 8; j++) { s += v[j]; s2 += v[j] * v[j]; }
#pragma unroll
  for (int off = 32; off > 0; off >>= 1) {
    s += __shfl_xor(s, off);
    s2 += __shfl_xor(s2, off);
  }
  const float mu = s * (1.f / 512.f);
  const float var = s2 * (1.f / 512.f) - mu * mu;
  const float inv = rsqrtf(var + 1e-5f);
  float4 w0 = *(const float4*)&lw[lane * 8];
  float4 w1 = *(const float4*)&lw[lane * 8 + 4];
  float4 b0 = *(const float4*)&lb[lane * 8];
  float4 b1 = *(const float4*)&lb[lane * 8 + 4];
  float4 o0 = make_float4((v[0] - mu) * inv * w0.x + b0.x, (v[1] - mu) * inv * w0.y + b0.y,
                          (v[2] - mu) * inv * w0.z + b0.z, (v[3] - mu) * inv * w0.w + b0.w);
  float4 o1 = make_float4((v[4] - mu) * inv * w1.x + b1.x, (v[5] - mu) * inv * w1.y + b1.y,
                          (v[6] - mu) * inv * w1.z + b1.z, (v[7] - mu) * inv * w1.w + b1.w);
  float* dst = out + (long)row * 512 + lane * 8;
  *(float4*)dst = o0;
  *(float4*)(dst + 4) = o1;
}

extern "C" void kernel_launch(void* const* d_in, const int* in_sizes, int n_in,
                              void* d_out, int out_size, void* d_ws, size_t ws_size,
                              hipStream_t stream) {
  const float* x = (const float*)d_in[0];
  const float* attn_bias = (const float*)d_in[1];
  const float* Wq = (const float*)d_in[2];
  const float* bq = (const float*)d_in[3];
  const float* Wk = (const float*)d_in[4];
  const float* bk = (const float*)d_in[5];
  const float* Wv = (const float*)d_in[6];
  const float* bv = (const float*)d_in[7];
  const float* Wp = (const float*)d_in[8];
  const float* bp = (const float*)d_in[9];
  const float* ln_w = (const float*)d_in[10];
  const float* ln_b = (const float*)d_in[11];
  const int* batch = (const int*)d_in[12];
  float* out = (float*)d_out;

  char* ws = (char*)d_ws;
  int* starts = (int*)ws;                        // 65 ints (512B reserved)
  short* Xbf = (short*)(ws + 512);               // NTOT x 512 bf16
  short* Wqb = Xbf + (long)NTOT * 512;
  short* Wkb = Wqb + 512 * 512;
  short* Wvb = Wkb + 512 * 512;
  short* Wpb = Wvb + 512 * 512;
  short* QKVbf = Wpb + 512 * 512;                // NTOT x 1536 bf16
  short* Obf = Xbf;                              // reuse: Xbf dead after QKV GEMM
  float* proj = (float*)QKVbf;                   // reuse: QKVbf dead after attention

  k_starts<<<(NTOT + 255) / 256, 256, 0, stream>>>(batch, starts);
  k_cvt<<<1537 + 4 * 128, 256, 0, stream>>>(x, Wq, Wk, Wv, Wp, Xbf, Wqb, Wkb, Wvb, Wpb);

  dim3 gq((NTOT + 127) / 128, 12);  // fused QKV: N = 1536, bf16 out
  k_gemm_mfma<true><<<gq, 256, 0, stream>>>(Xbf, Wqb, Wkb, Wvb, bq, bk, bv,
                                            nullptr, QKVbf, 1536, NTOT);

  dim3 ga(16, NB);  // (h, b)
  k_attn<<<ga, 256, 0, stream>>>(QKVbf, attn_bias, starts, Obf);

  dim3 gp((NTOT + 127) / 128, 4);  // proj: N = 512, residual fused, f32 out
  k_gemm_mfma<false><<<gp, 256, 0, stream>>>(Obf, Wpb, Wpb, Wpb, bp, bp, bp,
                                             x, proj, 512, NTOT);

  k_lnp<<<(NTOT + 3) / 4, 256, 0, stream>>>(proj, ln_w, ln_b, out);
}

// Round 8
// 99.803 us; speedup vs baseline: 1.0557x; 1.0199x over previous
//
#include <hip/hip_runtime.h>
#include <math.h>

#define NTOT 6148
#define NB 64
#define DM 512
#define SCALE_F 0.17677669529663687f

typedef __attribute__((ext_vector_type(8))) short bf16x8;
typedef __attribute__((ext_vector_type(4))) float f32x4;

__device__ __forceinline__ short f2bf(float f) {
  union { float f; unsigned u; } v; v.f = f;
  unsigned r = (v.u + 0x7fffu + ((v.u >> 16) & 1u)) >> 16;
  return (short)r;
}

__device__ __forceinline__ void gl_lds16(const void* g, void* l) {
  auto gp = (const __attribute__((address_space(1))) unsigned*)(unsigned long long)(uintptr_t)g;
  auto lp = (__attribute__((address_space(3))) unsigned*)(unsigned long long)(uintptr_t)l;
  __builtin_amdgcn_global_load_lds(gp, lp, 16, 0, 0);
}

// ---------------- starts from batch array ----------------
__global__ __launch_bounds__(256) void k_starts(const int* __restrict__ batch,
                                                int* __restrict__ starts) {
  int i = blockIdx.x * 256 + threadIdx.x;
  if (i >= NTOT) return;
  int b = batch[i];
  if (i == 0) starts[b] = 0;
  else if (batch[i - 1] != b) starts[b] = i;
  if (i == NTOT - 1) starts[NB] = NTOT;
}

// ---------------- f32 -> bf16 conversion (x + 4 weight matrices) ----------------
__global__ __launch_bounds__(256) void k_cvt(const float* __restrict__ x,
                                             const float* __restrict__ wq,
                                             const float* __restrict__ wk,
                                             const float* __restrict__ wv,
                                             const float* __restrict__ wp,
                                             short* __restrict__ xb,
                                             short* __restrict__ wqb,
                                             short* __restrict__ wkb,
                                             short* __restrict__ wvb,
                                             short* __restrict__ wpb) {
  const int bid = blockIdx.x;
  const float* s; short* d; long off;
  if (bid < 1537) {  // 1537*2048 == NTOT*512 exactly
    s = x; d = xb;
    off = ((long)bid * 256 + threadIdx.x) * 8;
  } else {
    int wi = (bid - 1537) >> 7;  // 128 blocks per 512x512 matrix
    s = (wi == 0) ? wq : (wi == 1) ? wk : (wi == 2) ? wv : wp;
    d = (wi == 0) ? wqb : (wi == 1) ? wkb : (wi == 2) ? wvb : wpb;
    off = ((long)((bid - 1537) & 127) * 256 + threadIdx.x) * 8;
  }
  float4 v0 = *(const float4*)(s + off);
  float4 v1 = *(const float4*)(s + off + 4);
  bf16x8 o;
  o[0] = f2bf(v0.x); o[1] = f2bf(v0.y); o[2] = f2bf(v0.z); o[3] = f2bf(v0.w);
  o[4] = f2bf(v1.x); o[5] = f2bf(v1.y); o[6] = f2bf(v1.z); o[7] = f2bf(v1.w);
  *(bf16x8*)(d + off) = o;
}

// ---------------- bf16 MFMA GEMM, 2-phase prefetch double-buffer ----------------
// C = A[M][512](bf16) @ W[N][512](bf16)^T + bias. 128x128 tile, BK=32, 4 waves.
// Grid: (n-blocks, m-blocks) — n fastest so consecutive blocks share the A panel.
template <bool BF16OUT>
__global__ __launch_bounds__(256) void k_gemm_mfma(
    const short* __restrict__ Abf,
    const short* __restrict__ W0, const short* __restrict__ W1, const short* __restrict__ W2,
    const float* __restrict__ b0, const float* __restrict__ b1, const float* __restrict__ b2,
    const float* __restrict__ resid, void* __restrict__ Cv, int ldc, int M) {
  __shared__ __align__(16) short As[2][128][32];
  __shared__ __align__(16) short Bs[2][128][32];
  const int tid = threadIdx.x;
  const int w = tid >> 6, l = tid & 63;
  const int m0 = blockIdx.y * 128;
  const int n0 = blockIdx.x * 128;
  const int sel = n0 >> 9;
  const short* Wt = (sel == 0) ? W0 : (sel == 1) ? W1 : W2;
  const float* bt = (sel == 0) ? b0 : (sel == 1) ? b1 : b2;
  const int nl0 = n0 & 511;
  const int wr = w >> 1, wc = w & 1;
  const int lr = l >> 2;        // row within 16-row DMA group
  const int lc = (l & 3) * 8;   // short offset of this lane's 16B chunk
  const int r0 = w * 32 + lr, r1 = r0 + 16;
  const long ga0 = (long)min(m0 + r0, M - 1) * 512 + lc;
  const long ga1 = (long)min(m0 + r1, M - 1) * 512 + lc;
  const long gb0 = (long)(nl0 + r0) * 512 + lc;
  const long gb1 = (long)(nl0 + r1) * 512 + lc;

  f32x4 acc[4][4];
#pragma unroll
  for (int m = 0; m < 4; m++)
#pragma unroll
    for (int n = 0; n < 4; n++) acc[m][n] = (f32x4){0.f, 0.f, 0.f, 0.f};

  const int fr = l & 15, fs = (l >> 4) * 8;

  // prologue: stage k-step 0
  gl_lds16(Abf + ga0, &As[0][w * 32][0]);
  gl_lds16(Abf + ga1, &As[0][w * 32 + 16][0]);
  gl_lds16(Wt + gb0, &Bs[0][w * 32][0]);
  gl_lds16(Wt + gb1, &Bs[0][w * 32 + 16][0]);
  __syncthreads();

  int cur = 0;
  for (int step = 0; step < 16; step++) {
    if (step < 15) {  // prefetch next k-step into the other buffer
      const int k0 = (step + 1) * 32;
      gl_lds16(Abf + ga0 + k0, &As[cur ^ 1][w * 32][0]);
      gl_lds16(Abf + ga1 + k0, &As[cur ^ 1][w * 32 + 16][0]);
      gl_lds16(Wt + gb0 + k0, &Bs[cur ^ 1][w * 32][0]);
      gl_lds16(Wt + gb1 + k0, &Bs[cur ^ 1][w * 32 + 16][0]);
    }
    bf16x8 af[4], bfr[4];
#pragma unroll
    for (int m = 0; m < 4; m++) af[m] = *(const bf16x8*)&As[cur][wr * 64 + m * 16 + fr][fs];
#pragma unroll
    for (int n = 0; n < 4; n++) bfr[n] = *(const bf16x8*)&Bs[cur][wc * 64 + n * 16 + fr][fs];
#pragma unroll
    for (int m = 0; m < 4; m++)
#pragma unroll
      for (int n = 0; n < 4; n++)
        acc[m][n] = __builtin_amdgcn_mfma_f32_16x16x32_bf16(af[m], bfr[n], acc[m][n], 0, 0, 0);
    __syncthreads();  // drains this iteration's prefetch (hidden under the MFMAs above)
    cur ^= 1;
  }

  // epilogue: C/D layout col=lane&15, row=(lane>>4)*4+j
  const int er = (l >> 4) * 4, ec = l & 15;
#pragma unroll
  for (int n = 0; n < 4; n++) {
    const int col = n0 + wc * 64 + n * 16 + ec;
    const float bv = bt[col & 511];
#pragma unroll
    for (int m = 0; m < 4; m++) {
      const int rowb = m0 + wr * 64 + m * 16 + er;
#pragma unroll
      for (int j = 0; j < 4; j++) {
        const int row = rowb + j;
        if (row < M) {
          float v = acc[m][n][j] + bv;
          if (resid) v += resid[(long)row * 512 + col];
          if (BF16OUT) ((short*)Cv)[(long)row * ldc + col] = f2bf(v);
          else ((float*)Cv)[(long)row * ldc + col] = v;
        }
      }
    }
  }
}

// ---------------- MFMA attention: one block per (h, b), 4 waves x 32 q-rows ----
// Bias panel DMA'd (global_load_lds, f32) into a per-wave LDS strip; softmax
// reads bias from LDS, then unnormalized bf16 P overwrites the same strip
// (reads of each m-half complete before its P writes; wave-local in-order LDS).
__global__ __launch_bounds__(256, 2) void k_attn(const short* __restrict__ QKVbf,
                                                 const float* __restrict__ bias,
                                                 const int* __restrict__ starts,
                                                 short* __restrict__ Obf) {
  __shared__ __align__(16) float BiasP[4][16][264];  // per-wave: 16 x (2 rows x 128 + 8 pad)
  __shared__ __align__(16) short Vtb[32][136];       // V transposed (rows = d)
  const int h = blockIdx.x, b = blockIdx.y;
  const int s0 = starts[b], cnt = starts[b + 1] - s0;
  const int tid = threadIdx.x, l = tid & 63, w = tid >> 6;
  const int wq0 = w * 32;
  const int lg = l >> 4, lk = l & 15, fs = lg * 8;
  const bool active = wq0 < cnt;
  short* Pw = (short*)&BiasP[w][0][0];  // P rows: 32 x 136 shorts, aliases bias strip

  // ---- issue V reg loads (own 32 k-rows, clamped => finite) ----
  const int u = l >> 2, c = (l & 3) * 8;
  const short* vbase = QKVbf + 1024 + h * 32 + c;
  const bf16x8 v0 = *(const bf16x8*)(vbase + (long)(s0 + min(wq0 + u, cnt - 1)) * 1536);
  const bf16x8 v1 = *(const bf16x8*)(vbase + (long)(s0 + min(wq0 + u + 16, cnt - 1)) * 1536);

  // ---- issue 16x 1KB bias DMA (fire-and-forget, no VGPRs) ----
  const float* bbase = bias + ((long)(b * 16 + h) << 14);
  if (active) {
    const float* bsrc = bbase + (long)wq0 * 128 + l * 4;  // lane's 16B within each 1KB chunk
#pragma unroll
    for (int t = 0; t < 16; t++)
      gl_lds16(bsrc + t * 256, &BiasP[w][t][0]);
  }

  // ---- issue Q/K fragment reg loads ----
  bf16x8 aq[2], bk[8];
  if (active) {
    const short* qbase = QKVbf + h * 32 + fs;
#pragma unroll
    for (int m = 0; m < 2; m++)
      aq[m] = *(const bf16x8*)(qbase + (long)(s0 + min(wq0 + m * 16 + lk, cnt - 1)) * 1536);
#pragma unroll
    for (int n = 0; n < 8; n++)
      bk[n] = *(const bf16x8*)(qbase + 512 + (long)(s0 + min(n * 16 + lk, cnt - 1)) * 1536);
  }

  // ---- V scatter-transpose into LDS (rows >= cnt finite, killed by P==0) ----
#pragma unroll
  for (int i = 0; i < 8; i++) Vtb[c + i][wq0 + u] = v0[i];
#pragma unroll
  for (int i = 0; i < 8; i++) Vtb[c + i][wq0 + u + 16] = v1[i];

  f32x4 S[2][8];
  float invs[2][4];
  if (active) {
    // ---- S = Q K^T (16 MFMA) ----
#pragma unroll
    for (int n = 0; n < 8; n++)
#pragma unroll
      for (int m = 0; m < 2; m++)
        S[m][n] = __builtin_amdgcn_mfma_f32_16x16x32_bf16(aq[m], bk[n],
                                                          (f32x4){0.f, 0.f, 0.f, 0.f}, 0, 0, 0);
    // DMA has no dest reg: explicitly drain before reading the bias strip
    asm volatile("s_waitcnt vmcnt(0)" ::: "memory");
    __builtin_amdgcn_sched_barrier(0);

    // ---- bias(LDS,f32) + scale + mask + softmax; unnormalized P -> strip ----
#pragma unroll
    for (int m = 0; m < 2; m++) {
      const int rb = m * 16 + lg * 4;  // local q row base
#pragma unroll
      for (int n = 0; n < 8; n++) {
        const int k = n * 16 + lk;
        const bool kok = k < cnt;
#pragma unroll
        for (int j = 0; j < 4; j++) {
          const int r = rb + j;
          const float sv = S[m][n][j] * SCALE_F + BiasP[w][r >> 1][(r & 1) * 128 + k];
          S[m][n][j] = kok ? sv : -1e30f;
        }
      }
#pragma unroll
      for (int j = 0; j < 4; j++) {
        float mx = S[m][0][j];
#pragma unroll
        for (int n = 1; n < 8; n++) mx = fmaxf(mx, S[m][n][j]);
        mx = fmaxf(mx, __shfl_xor(mx, 1));
        mx = fmaxf(mx, __shfl_xor(mx, 2));
        mx = fmaxf(mx, __shfl_xor(mx, 4));
        mx = fmaxf(mx, __shfl_xor(mx, 8));
        float sum = 0.f;
#pragma unroll
        for (int n = 0; n < 8; n++) {
          const float p = __expf(S[m][n][j] - mx);
          S[m][n][j] = p;
          sum += p;
        }
        sum += __shfl_xor(sum, 1);
        sum += __shfl_xor(sum, 2);
        sum += __shfl_xor(sum, 4);
        sum += __shfl_xor(sum, 8);
        invs[m][j] = 1.f / sum;
        const int r = rb + j;
#pragma unroll
        for (int n = 0; n < 8; n++) Pw[r * 136 + n * 16 + lk] = f2bf(S[m][n][j]);
      }
    }
  }

  __syncthreads();  // V (cross-wave) visibility; P/bias strips are wave-local
  if (!active) return;

  // ---- O = P V (16 MFMA), same-wave LDS RAW ----
  f32x4 O[2][2];
#pragma unroll
  for (int m = 0; m < 2; m++)
#pragma unroll
    for (int dt = 0; dt < 2; dt++) O[m][dt] = (f32x4){0.f, 0.f, 0.f, 0.f};
#pragma unroll
  for (int kc = 0; kc < 4; kc++) {
    bf16x8 pa[2], vb[2];
#pragma unroll
    for (int m = 0; m < 2; m++)
      pa[m] = *(const bf16x8*)&Pw[(m * 16 + lk) * 136 + kc * 32 + fs];
#pragma unroll
    for (int dt = 0; dt < 2; dt++) vb[dt] = *(const bf16x8*)&Vtb[dt * 16 + lk][kc * 32 + fs];
#pragma unroll
    for (int m = 0; m < 2; m++)
#pragma unroll
      for (int dt = 0; dt < 2; dt++)
        O[m][dt] = __builtin_amdgcn_mfma_f32_16x16x32_bf16(pa[m], vb[dt], O[m][dt], 0, 0, 0);
  }
  // ---- store O (bf16), fold in 1/sum ----
#pragma unroll
  for (int m = 0; m < 2; m++) {
    const int qb0 = wq0 + m * 16 + lg * 4;
#pragma unroll
    for (int j = 0; j < 4; j++) {
      if (qb0 + j < cnt) {
        short* orow = Obf + (long)(s0 + qb0 + j) * 512 + h * 32;
#pragma unroll
        for (int dt = 0; dt < 2; dt++)
          orow[dt * 16 + lk] = f2bf(O[m][dt][j] * invs[m][j]);
      }
    }
  }
}

// ---------------- LayerNorm (residual pre-added), one wave per row ----------------
__global__ __launch_bounds__(256) void k_lnp(const float* __restrict__ pre,
                                             const float* __restrict__ lw,
                                             const float* __restrict__ lb,
                                             float* __restrict__ out) {
  const int row = blockIdx.x * 4 + (threadIdx.x >> 6);
  if (row >= NTOT) return;
  const int lane = threadIdx.x & 63;
  const float* pr = pre + (long)row * 512 + lane * 8;
  float4 p0 = *(const float4*)pr;
  float4 p1 = *(const float4*)(pr + 4);
  float v[8] = {p0.x, p0.y, p0.z, p0.w, p1.x, p1.y, p1.z, p1.w};
  float s = 0.f, s2 = 0.f;
#pragma unroll
  for (int j = 0; j < 8; j++) { s += v[j]; s2 += v[j] * v[j]; }
#pragma unroll
  for (int off = 32; off > 0; off >>= 1) {
    s += __shfl_xor(s, off);
    s2 += __shfl_xor(s2, off);
  }
  const float mu = s * (1.f / 512.f);
  const float var = s2 * (1.f / 512.f) - mu * mu;
  const float inv = rsqrtf(var + 1e-5f);
  float4 w0 = *(const float4*)&lw[lane * 8];
  float4 w1 = *(const float4*)&lw[lane * 8 + 4];
  float4 b0 = *(const float4*)&lb[lane * 8];
  float4 b1 = *(const float4*)&lb[lane * 8 + 4];
  float4 o0 = make_float4((v[0] - mu) * inv * w0.x + b0.x, (v[1] - mu) * inv * w0.y + b0.y,
                          (v[2] - mu) * inv * w0.z + b0.z, (v[3] - mu) * inv * w0.w + b0.w);
  float4 o1 = make_float4((v[4] - mu) * inv * w1.x + b1.x, (v[5] - mu) * inv * w1.y + b1.y,
                          (v[6] - mu) * inv * w1.z + b1.z, (v[7] - mu) * inv * w1.w + b1.w);
  float* dst = out + (long)row * 512 + lane * 8;
  *(float4*)dst = o0;
  *(float4*)(dst + 4) = o1;
}

extern "C" void kernel_launch(void* const* d_in, const int* in_sizes, int n_in,
                              void* d_out, int out_size, void* d_ws, size_t ws_size,
                              hipStream_t stream) {
  const float* x = (const float*)d_in[0];
  const float* attn_bias = (const float*)d_in[1];
  const float* Wq = (const float*)d_in[2];
  const float* bq = (const float*)d_in[3];
  const float* Wk = (const float*)d_in[4];
  const float* bk = (const float*)d_in[5];
  const float* Wv = (const float*)d_in[6];
  const float* bv = (const float*)d_in[7];
  const float* Wp = (const float*)d_in[8];
  const float* bp = (const float*)d_in[9];
  const float* ln_w = (const float*)d_in[10];
  const float* ln_b = (const float*)d_in[11];
  const int* batch = (const int*)d_in[12];
  float* out = (float*)d_out;

  char* ws = (char*)d_ws;
  int* starts = (int*)ws;                        // 65 ints (512B reserved)
  short* Xbf = (short*)(ws + 512);               // NTOT x 512 bf16
  short* Wqb = Xbf + (long)NTOT * 512;
  short* Wkb = Wqb + 512 * 512;
  short* Wvb = Wkb + 512 * 512;
  short* Wpb = Wvb + 512 * 512;
  short* QKVbf = Wpb + 512 * 512;                // NTOT x 1536 bf16
  short* Obf = Xbf;                              // reuse: Xbf dead after QKV GEMM
  float* proj = (float*)QKVbf;                   // reuse: QKVbf dead after attention

  k_starts<<<(NTOT + 255) / 256, 256, 0, stream>>>(batch, starts);
  k_cvt<<<1537 + 4 * 128, 256, 0, stream>>>(x, Wq, Wk, Wv, Wp, Xbf, Wqb, Wkb, Wvb, Wpb);

  dim3 gq(12, (NTOT + 127) / 128);  // fused QKV: N = 1536 (n fastest), bf16 out
  k_gemm_mfma<true><<<gq, 256, 0, stream>>>(Xbf, Wqb, Wkb, Wvb, bq, bk, bv,
                                            nullptr, QKVbf, 1536, NTOT);

  dim3 ga(16, NB);  // (h, b)
  k_attn<<<ga, 256, 0, stream>>>(QKVbf, attn_bias, starts, Obf);

  dim3 gp(4, (NTOT + 127) / 128);  // proj: N = 512, residual fused, f32 out
  k_gemm_mfma<false><<<gp, 256, 0, stream>>>(Obf, Wpb, Wpb, Wpb, bp, bp, bp,
                                             x, proj, 512, NTOT);

  k_lnp<<<(NTOT + 3) / 4, 256, 0, stream>>>(proj, ln_w, ln_b, out);
}